// Round 1
// baseline (306.191 us; speedup 1.0000x reference)
//
#include <hip/hip_runtime.h>
#include <hip/hip_bf16.h>

// Problem dims (fixed by reference): E=8, D=2048, B=4096, 3 layers.
#define MDIM 4096
#define NDIM 2048
#define KDIM 2048
#define BM 128
#define BN 128
#define BK 64

typedef __attribute__((ext_vector_type(8))) short bf16x8;   // 8 bf16 (4 VGPRs)
typedef __attribute__((ext_vector_type(4))) float f32x4;    // MFMA accumulator

__device__ __forceinline__ unsigned short f2bf(float f) {
    unsigned u = __builtin_bit_cast(unsigned, f);
    u += 0x7FFFu + ((u >> 16) & 1u);        // round-to-nearest-even
    return (unsigned short)(u >> 16);
}

// ---------------------------------------------------------------------------
// Kernel 1: blend experts (f32 accumulate, bf16 store) + convert x to bf16.
// Reads 402MB of W + 32MB x -> memory-bound.
// ---------------------------------------------------------------------------
__global__ __launch_bounds__(256) void blend_convert_kernel(
    const float* __restrict__ W, const float* __restrict__ cb,
    const float* __restrict__ x,
    unsigned short* __restrict__ wb, unsigned short* __restrict__ xb)
{
    float c[8];
#pragma unroll
    for (int e = 0; e < 8; ++e) c[e] = cb[e];
    const unsigned per_layer = 4194304u;            // 2048*2048
    const unsigned wtotal4 = 3u * (per_layer >> 2); // 3,145,728 float4 units
    const unsigned xtotal4 = 2097152u;              // 8M / 4
    const unsigned total = wtotal4 + xtotal4;
    unsigned stride = gridDim.x * blockDim.x;
    for (unsigned i = blockIdx.x * blockDim.x + threadIdx.x; i < total; i += stride) {
        if (i < wtotal4) {
            unsigned layer = i >> 20;                // per_layer/4 = 2^20
            unsigned off = (i & 1048575u) << 2;      // element offset in layer
            const float* base = W + (size_t)layer * 8u * per_layer + off;
            float4 s = make_float4(0.f, 0.f, 0.f, 0.f);
#pragma unroll
            for (int e = 0; e < 8; ++e) {
                float4 v = *(const float4*)(base + (size_t)e * per_layer);
                s.x += c[e] * v.x; s.y += c[e] * v.y;
                s.z += c[e] * v.z; s.w += c[e] * v.w;
            }
            ushort4 o;
            o.x = f2bf(s.x); o.y = f2bf(s.y); o.z = f2bf(s.z); o.w = f2bf(s.w);
            *(ushort4*)(wb + (size_t)layer * per_layer + off) = o;
        } else {
            unsigned j = (i - wtotal4) << 2;
            float4 v = *(const float4*)(x + j);
            ushort4 o;
            o.x = f2bf(v.x); o.y = f2bf(v.y); o.z = f2bf(v.z); o.w = f2bf(v.w);
            *(ushort4*)(xb + j) = o;
        }
    }
}

// ---------------------------------------------------------------------------
// Kernel 2: bf16 GEMM, C[M,N] = A[M,K] * Bw[N,K]^T + bias, optional ELU.
// m97 structure: 128x128 tile, BK=64, 4 waves (2x2) each owning 64x64,
// 4x4 fragments of mfma_f32_16x16x32_bf16, global_load_lds width-16 staging.
// ---------------------------------------------------------------------------
template<int ACT, typename OutT>
__global__ __launch_bounds__(256, 2) void gemm_bt(
    const unsigned short* __restrict__ A,   // M x K bf16 bits
    const unsigned short* __restrict__ Bw,  // N x K bf16 bits
    const float* __restrict__ bias,         // N
    OutT* __restrict__ C)                   // M x N
{
    __shared__ unsigned short ldsA[BM * BK];   // [128][64] linear, 16KB
    __shared__ unsigned short ldsB[BN * BK];

    const int tid = threadIdx.x;
    const int wid = tid >> 6;          // wave 0..3
    const int lane = tid & 63;
    const int wr = wid >> 1;           // wave row (M) 0..1
    const int wc = wid & 1;            // wave col (N) 0..1

    const int bid = blockIdx.x;
    const int tm = bid >> 4;           // NDIM/BN = 16 tiles in N
    const int tn = bid & 15;
    const int blockM = tm * BM;
    const int blockN = tn * BN;

    f32x4 acc[4][4];
#pragma unroll
    for (int i = 0; i < 4; ++i)
#pragma unroll
        for (int j = 0; j < 4; ++j) acc[i][j] = (f32x4){0.f, 0.f, 0.f, 0.f};

    // staging geometry: 1024B LDS chunk per global_load_lds (64 lanes x 16B).
    // chunk c covers tile rows 8c..8c+7; lane l -> row 8c+(l>>3), col (l&7)*8.
    const int srow = lane >> 3;
    const int scol = (lane & 7) * 8;

    for (int k0 = 0; k0 < KDIM; k0 += BK) {
#pragma unroll
        for (int c4 = 0; c4 < 4; ++c4) {
            const int c = wid * 4 + c4;                     // chunk 0..15
            const unsigned short* gA = &A[(size_t)(blockM + c * 8 + srow) * KDIM + k0 + scol];
            __builtin_amdgcn_global_load_lds(
                (const __attribute__((address_space(1))) void*)gA,
                (__attribute__((address_space(3))) void*)&ldsA[c * 512],
                16, 0, 0);
            const unsigned short* gB = &Bw[(size_t)(blockN + c * 8 + srow) * KDIM + k0 + scol];
            __builtin_amdgcn_global_load_lds(
                (const __attribute__((address_space(1))) void*)gB,
                (__attribute__((address_space(3))) void*)&ldsB[c * 512],
                16, 0, 0);
        }
        __syncthreads();   // compiler drains vmcnt before s_barrier

#pragma unroll
        for (int kk = 0; kk < 2; ++kk) {
            bf16x8 afrag[4], bfrag[4];
            const int krd = kk * 32 + (lane >> 4) * 8;  // k-offset for this lane
#pragma unroll
            for (int m = 0; m < 4; ++m) {
                const int row = wr * 64 + m * 16 + (lane & 15);
                afrag[m] = *(const bf16x8*)&ldsA[row * BK + krd];
            }
#pragma unroll
            for (int n = 0; n < 4; ++n) {
                const int rowb = wc * 64 + n * 16 + (lane & 15);
                bfrag[n] = *(const bf16x8*)&ldsB[rowb * BK + krd];
            }
#pragma unroll
            for (int m = 0; m < 4; ++m)
#pragma unroll
                for (int n = 0; n < 4; ++n)
                    acc[m][n] = __builtin_amdgcn_mfma_f32_16x16x32_bf16(
                        afrag[m], bfrag[n], acc[m][n], 0, 0, 0);
        }
        __syncthreads();
    }

    // epilogue: C/D layout col=lane&15 (N), row=(lane>>4)*4+reg (M)
    const int crow = (lane >> 4) * 4;
    const int ccol = lane & 15;
#pragma unroll
    for (int m = 0; m < 4; ++m) {
#pragma unroll
        for (int n = 0; n < 4; ++n) {
            const int col = blockN + wc * 64 + n * 16 + ccol;
            const float bv = bias[col];
#pragma unroll
            for (int r = 0; r < 4; ++r) {
                const int row = blockM + wr * 64 + m * 16 + crow + r;
                float v = acc[m][n][r] + bv;
                if (ACT) v = v > 0.f ? v : expm1f(v);
                if constexpr (sizeof(OutT) == 2) {
                    C[(size_t)row * NDIM + col] = (OutT)f2bf(v);
                } else {
                    C[(size_t)row * NDIM + col] = (OutT)v;
                }
            }
        }
    }
}

// ---------------------------------------------------------------------------
// Launch: blend+convert, then 3 chained GEMMs.
// Workspace layout (ushort units):
//   wb  [3 * 4194304]  blended bf16 weights (24 MB)
//   xb  [8388608]      x in bf16 (16 MB)    -- reused as y1 after GEMM0
//   y0  [8388608]      layer-0 output bf16 (16 MB)
// total 56 MB.
// ---------------------------------------------------------------------------
extern "C" void kernel_launch(void* const* d_in, const int* in_sizes, int n_in,
                              void* d_out, int out_size, void* d_ws, size_t ws_size,
                              hipStream_t stream) {
    const float* blendw = (const float*)d_in[0];   // (8,)
    const float* x      = (const float*)d_in[1];   // (4096, 2048)
    const float* W      = (const float*)d_in[2];   // (3, 8, 2048, 2048)
    const float* Bb     = (const float*)d_in[3];   // (3, 2048)
    float* out = (float*)d_out;                    // (4096, 2048) f32

    unsigned short* wb = (unsigned short*)d_ws;
    unsigned short* xb = wb + (size_t)3 * 4194304;
    unsigned short* y0 = xb + 8388608;
    unsigned short* y1 = xb;   // reuse: xb dead after GEMM0

    blend_convert_kernel<<<2048, 256, 0, stream>>>(W, blendw, x, wb, xb);

    const int grid = (MDIM / BM) * (NDIM / BN);    // 512
    gemm_bt<1, unsigned short><<<grid, 256, 0, stream>>>(xb, wb,               Bb,        y0);
    gemm_bt<1, unsigned short><<<grid, 256, 0, stream>>>(y0, wb + 4194304,     Bb + 2048, y1);
    gemm_bt<0, float        ><<<grid, 256, 0, stream>>>(y1, wb + 2 * 4194304,  Bb + 4096, out);
}

// Round 2
// 294.742 us; speedup vs baseline: 1.0388x; 1.0388x over previous
//
#include <hip/hip_runtime.h>
#include <hip/hip_bf16.h>

// Problem dims (fixed by reference): E=8, D=2048, B=4096, 3 layers.
#define MDIM 4096
#define NDIM 2048
#define KDIM 2048
#define KTILES 32          // K / 64
#define NITER  16          // KTILES / 2

typedef __attribute__((ext_vector_type(8))) short bf16x8;   // 8 bf16 (4 VGPRs)
typedef __attribute__((ext_vector_type(4))) float f32x4;    // MFMA accumulator

__device__ __forceinline__ unsigned short f2bf(float f) {
    unsigned u = __builtin_bit_cast(unsigned, f);
    u += 0x7FFFu + ((u >> 16) & 1u);        // round-to-nearest-even
    return (unsigned short)(u >> 16);
}

// ---------------------------------------------------------------------------
// Kernel 1: blend experts (f32 accumulate, bf16 store) + convert x to bf16.
// Reads 402MB of W + 32MB x -> memory-bound, ~70us at ~6.5TB/s.
// ---------------------------------------------------------------------------
__global__ __launch_bounds__(256) void blend_convert_kernel(
    const float* __restrict__ W, const float* __restrict__ cb,
    const float* __restrict__ x,
    unsigned short* __restrict__ wb, unsigned short* __restrict__ xb)
{
    float c[8];
#pragma unroll
    for (int e = 0; e < 8; ++e) c[e] = cb[e];
    const unsigned per_layer = 4194304u;            // 2048*2048
    const unsigned wtotal4 = 3u * (per_layer >> 2); // 3,145,728 float4 units
    const unsigned xtotal4 = 2097152u;              // 8M / 4
    const unsigned total = wtotal4 + xtotal4;
    unsigned stride = gridDim.x * blockDim.x;
    for (unsigned i = blockIdx.x * blockDim.x + threadIdx.x; i < total; i += stride) {
        if (i < wtotal4) {
            unsigned layer = i >> 20;                // per_layer/4 = 2^20
            unsigned off = (i & 1048575u) << 2;      // element offset in layer
            const float* base = W + (size_t)layer * 8u * per_layer + off;
            float4 s = make_float4(0.f, 0.f, 0.f, 0.f);
#pragma unroll
            for (int e = 0; e < 8; ++e) {
                float4 v = *(const float4*)(base + (size_t)e * per_layer);
                s.x += c[e] * v.x; s.y += c[e] * v.y;
                s.z += c[e] * v.z; s.w += c[e] * v.w;
            }
            ushort4 o;
            o.x = f2bf(s.x); o.y = f2bf(s.y); o.z = f2bf(s.z); o.w = f2bf(s.w);
            *(ushort4*)(wb + (size_t)layer * per_layer + off) = o;
        } else {
            unsigned j = (i - wtotal4) << 2;
            float4 v = *(const float4*)(x + j);
            ushort4 o;
            o.x = f2bf(v.x); o.y = f2bf(v.y); o.z = f2bf(v.z); o.w = f2bf(v.w);
            *(ushort4*)(xb + j) = o;
        }
    }
}

// ---------------------------------------------------------------------------
// Kernel 2: 256x256 8-phase bf16 GEMM (m201 template port, plain HIP).
//   C[M,N] = A[M,K] * Bw[N,K]^T + bias, optional ELU.
// 512 threads = 8 waves (2 wave-rows x 4 wave-cols); wave output 128x64 via
// interleaved quadrants: rows {wr*64 + qm*128 + 0..63}, cols {wc*32 + qn*128
// + 0..31} -> each phase (qm,qn) touches exactly one A-half and one B-half.
// LDS 128KB: A[2buf][2half][128][64] + B likewise, bf16, XOR-16B swizzled.
// One half-tile stage (2x global_load_lds w16) per phase; vmcnt(4) at P4/P8.
// ---------------------------------------------------------------------------
#define BARR() do { asm volatile("" ::: "memory"); __builtin_amdgcn_s_barrier(); asm volatile("" ::: "memory"); } while (0)
#define SP(N) __builtin_amdgcn_s_setprio(N)
#define VMC(N) asm volatile("s_waitcnt vmcnt(" #N ")" ::: "memory")

#define LDSA(BUF, HALF) ((BUF) * 32768 + (HALF) * 16384)
#define LDSB(BUF, HALF) (65536 + (BUF) * 32768 + (HALF) * 16384)

template<int ACT, typename OutT>
__global__ __launch_bounds__(512, 2) void gemm8p(
    const unsigned short* __restrict__ A,   // M x K bf16 bits
    const unsigned short* __restrict__ Bw,  // N x K bf16 bits
    const float* __restrict__ bias,         // N
    OutT* __restrict__ C)                   // M x N
{
    __shared__ __align__(16) unsigned short lds[65536];   // 128 KB
    char* ldsc = (char*)lds;

    const int tid = threadIdx.x;
    const int wid = tid >> 6;
    const int lane = tid & 63;
    const int wr = wid >> 2;      // 0..1
    const int wc = wid & 3;       // 0..3

    const long blockM = (long)(blockIdx.x >> 3) * 256;   // 16 M-tiles
    const long blockN = (long)(blockIdx.x & 7) * 256;    // 8 N-tiles

    // ds_read addressing: row-in-half + XOR swizzle of the 16B column slot.
    const int rA = wr * 64 + (lane & 15);
    const int rB = wc * 32 + (lane & 15);
    const int sw = (lane & 7) << 4;          // swizzle XOR (bytes); (row&7)<<4
    const int ck = (lane >> 4) << 4;         // k-slot byte base

    // staging: thread t writes LDS linear bytes [t*16, t*16+16) of a half;
    // source column pre-XORed so LDS[row][phys] = G[row][phys ^ ((row&7)<<4)].
    const int srow = tid >> 3;                                  // 0..63 (+64 for issue 2)
    const int scol = ((tid & 7) ^ (srow & 7)) << 3;             // element offset
    const unsigned short* aStage = A + (blockM + srow) * KDIM + scol;
    const unsigned short* bStage = Bw + (blockN + srow) * KDIM + scol;

#define STAGE_A(BUF, HALF, KT) do { \
    const unsigned short* g_ = aStage + (size_t)(HALF) * 128 * KDIM + (size_t)(KT) * 64; \
    char* l_ = ldsc + LDSA(BUF, HALF) + wid * 1024; \
    __builtin_amdgcn_global_load_lds((const __attribute__((address_space(1))) void*)g_, \
        (__attribute__((address_space(3))) void*)l_, 16, 0, 0); \
    __builtin_amdgcn_global_load_lds((const __attribute__((address_space(1))) void*)(g_ + (size_t)64 * KDIM), \
        (__attribute__((address_space(3))) void*)(l_ + 8192), 16, 0, 0); \
} while (0)

#define STAGE_B(BUF, HALF, KT) do { \
    const unsigned short* g_ = bStage + (size_t)(HALF) * 128 * KDIM + (size_t)(KT) * 64; \
    char* l_ = ldsc + LDSB(BUF, HALF) + wid * 1024; \
    __builtin_amdgcn_global_load_lds((const __attribute__((address_space(1))) void*)g_, \
        (__attribute__((address_space(3))) void*)l_, 16, 0, 0); \
    __builtin_amdgcn_global_load_lds((const __attribute__((address_space(1))) void*)(g_ + (size_t)64 * KDIM), \
        (__attribute__((address_space(3))) void*)(l_ + 8192), 16, 0, 0); \
} while (0)

#define RD_A(RB, QM, M, KK) \
    (*(const bf16x8*)(ldsc + LDSA(RB, QM) + (rA + (M) * 16) * 128 + (((KK) * 64 + ck) ^ sw)))
#define RD_B(RB, QN, N, KK) \
    (*(const bf16x8*)(ldsc + LDSB(RB, QN) + (rB + (N) * 16) * 128 + (((KK) * 64 + ck) ^ sw)))

    f32x4 acc[2][2][4][2];
#pragma unroll
    for (int a = 0; a < 2; ++a)
#pragma unroll
        for (int b = 0; b < 2; ++b)
#pragma unroll
            for (int m = 0; m < 4; ++m)
#pragma unroll
                for (int n = 0; n < 2; ++n) acc[a][b][m][n] = (f32x4){0.f, 0.f, 0.f, 0.f};

    bf16x8 af[4][2], b0[2][2], b1[2][2];

#define READ_AQ(RB, QM) do { _Pragma("unroll") for (int m_ = 0; m_ < 4; ++m_) { \
    af[m_][0] = RD_A(RB, QM, m_, 0); af[m_][1] = RD_A(RB, QM, m_, 1); } } while (0)
#define READ_B(DST, RB, QN) do { \
    DST[0][0] = RD_B(RB, QN, 0, 0); DST[0][1] = RD_B(RB, QN, 0, 1); \
    DST[1][0] = RD_B(RB, QN, 1, 0); DST[1][1] = RD_B(RB, QN, 1, 1); } while (0)
#define DO_MFMA(QM, QN, B) do { _Pragma("unroll") for (int m_ = 0; m_ < 4; ++m_) \
    _Pragma("unroll") for (int n_ = 0; n_ < 2; ++n_) { \
        acc[QM][QN][m_][n_] = __builtin_amdgcn_mfma_f32_16x16x32_bf16(af[m_][0], B[n_][0], acc[QM][QN][m_][n_], 0, 0, 0); \
        acc[QM][QN][m_][n_] = __builtin_amdgcn_mfma_f32_16x16x32_bf16(af[m_][1], B[n_][1], acc[QM][QN][m_][n_], 0, 0, 0); } } while (0)

    // ---- prologue: tile0 fully into buf0; tile1 A.h0,B.h1 into buf1 ----
    STAGE_A(0, 0, 0); STAGE_B(0, 0, 0); STAGE_A(0, 1, 0); STAGE_B(0, 1, 0);
    STAGE_A(1, 0, 1); STAGE_B(1, 1, 1);
    VMC(4);                       // tile0 complete; tile1's 2 stages may fly
    __builtin_amdgcn_s_barrier();
    asm volatile("" ::: "memory");

#pragma unroll 1
    for (int i = 0; i < NITER; ++i) {
        const int t1 = 2 * i + 1, t2 = 2 * i + 2, t3 = 2 * i + 3;
        // P1: compute (qm0,qn0) of tile 2i (buf0); stage t1.A.h1 -> buf1
        READ_AQ(0, 0); READ_B(b0, 0, 0);
        STAGE_A(1, 1, t1);
        BARR(); SP(1); DO_MFMA(0, 0, b0); SP(0); BARR();
        // P2: (qm0,qn1); stage t1.B.h0 -> buf1
        READ_B(b1, 0, 1);
        STAGE_B(1, 0, t1);
        BARR(); SP(1); DO_MFMA(0, 1, b1); SP(0); BARR();
        // P3: (qm1,qn1); stage t2.A.h0 -> buf0 (A.h0 free after P2)
        READ_AQ(0, 1);
        if (t2 < KTILES) STAGE_A(0, 0, t2);
        BARR(); SP(1); DO_MFMA(1, 1, b1); SP(0); BARR();
        // P4: (qm1,qn0) reuses b0; stage t2.B.h1 -> buf0 (free after P3)
        if (t2 < KTILES) STAGE_B(0, 1, t2);
        BARR(); SP(1); DO_MFMA(1, 0, b0); SP(0);
        if (t2 < KTILES) { VMC(4); } else { VMC(0); }   // tile 2i+1 ready
        BARR();
        // P5: tile 2i+1 (buf1) (qm0,qn0); stage t2.A.h1 -> buf0 (free after P4)
        READ_AQ(1, 0); READ_B(b0, 1, 0);
        if (t2 < KTILES) STAGE_A(0, 1, t2);
        BARR(); SP(1); DO_MFMA(0, 0, b0); SP(0); BARR();
        // P6: (qm0,qn1); stage t2.B.h0 -> buf0 (free after P4)
        READ_B(b1, 1, 1);
        if (t2 < KTILES) STAGE_B(0, 0, t2);
        BARR(); SP(1); DO_MFMA(0, 1, b1); SP(0); BARR();
        // P7: (qm1,qn1); stage t3.A.h0 -> buf1 (free after P6)
        READ_AQ(1, 1);
        if (t3 < KTILES) STAGE_A(1, 0, t3);
        BARR(); SP(1); DO_MFMA(1, 1, b1); SP(0); BARR();
        // P8: (qm1,qn0) reuses b0; stage t3.B.h1 -> buf1 (free after P7)
        if (t3 < KTILES) STAGE_B(1, 1, t3);
        BARR(); SP(1); DO_MFMA(1, 0, b0); SP(0);
        VMC(4);                                          // tile 2i+2 ready
        BARR();
    }

    // ---- epilogue: C/D layout col=lane&15 (N), row=(lane>>4)*4+reg (M) ----
    const int crow = (lane >> 4) * 4;
    const int ccol = lane & 15;
#pragma unroll
    for (int qm = 0; qm < 2; ++qm)
#pragma unroll
        for (int qn = 0; qn < 2; ++qn)
#pragma unroll
            for (int m = 0; m < 4; ++m)
#pragma unroll
                for (int n = 0; n < 2; ++n) {
                    const long col = blockN + qn * 128 + wc * 32 + n * 16 + ccol;
                    const float bv = bias[col];
#pragma unroll
                    for (int r = 0; r < 4; ++r) {
                        const long row = blockM + qm * 128 + wr * 64 + m * 16 + crow + r;
                        float v = acc[qm][qn][m][n][r] + bv;
                        if (ACT) v = v > 0.f ? v : expm1f(v);
                        if constexpr (sizeof(OutT) == 2) {
                            C[row * NDIM + col] = (OutT)f2bf(v);
                        } else {
                            C[row * NDIM + col] = (OutT)v;
                        }
                    }
                }
#undef STAGE_A
#undef STAGE_B
#undef RD_A
#undef RD_B
#undef READ_AQ
#undef READ_B
#undef DO_MFMA
}

// ---------------------------------------------------------------------------
// Launch: blend+convert, then 3 chained GEMMs.
// Workspace (ushort units): wb[3*4194304] weights, xb[8388608], y0[8388608].
// ---------------------------------------------------------------------------
extern "C" void kernel_launch(void* const* d_in, const int* in_sizes, int n_in,
                              void* d_out, int out_size, void* d_ws, size_t ws_size,
                              hipStream_t stream) {
    const float* blendw = (const float*)d_in[0];   // (8,)
    const float* x      = (const float*)d_in[1];   // (4096, 2048)
    const float* W      = (const float*)d_in[2];   // (3, 8, 2048, 2048)
    const float* Bb     = (const float*)d_in[3];   // (3, 2048)
    float* out = (float*)d_out;                    // (4096, 2048) f32

    unsigned short* wb = (unsigned short*)d_ws;
    unsigned short* xb = wb + (size_t)3 * 4194304;
    unsigned short* y0 = xb + 8388608;
    unsigned short* y1 = xb;   // reuse: xb dead after GEMM0

    blend_convert_kernel<<<2048, 256, 0, stream>>>(W, blendw, x, wb, xb);

    const int grid = (MDIM / 256) * (NDIM / 256);    // 128 blocks
    gemm8p<1, unsigned short><<<grid, 512, 0, stream>>>(xb, wb,               Bb,        y0);
    gemm8p<1, unsigned short><<<grid, 512, 0, stream>>>(y0, wb + 4194304,     Bb + 2048, y1);
    gemm8p<0, float        ><<<grid, 512, 0, stream>>>(y1, wb + 2 * 4194304,  Bb + 4096, out);
}

// Round 3
// 261.345 us; speedup vs baseline: 1.1716x; 1.1278x over previous
//
#include <hip/hip_runtime.h>
#include <hip/hip_bf16.h>

// Problem dims (fixed by reference): E=8, D=2048, B=4096, 3 layers.
#define MDIM 4096
#define NDIM 2048
#define KDIM 2048
#define KTILES 32          // K / 64

typedef __attribute__((ext_vector_type(8))) short bf16x8;   // 8 bf16 (4 VGPRs)
typedef __attribute__((ext_vector_type(4))) float f32x4;    // MFMA accumulator

__device__ __forceinline__ unsigned short f2bf(float f) {
    unsigned u = __builtin_bit_cast(unsigned, f);
    u += 0x7FFFu + ((u >> 16) & 1u);        // round-to-nearest-even
    return (unsigned short)(u >> 16);
}

// ---------------------------------------------------------------------------
// Kernel 1: blend experts (f32 accumulate, bf16 store) + convert x to bf16.
// Reads 402MB of W + 32MB x -> memory-bound, ~70us.
// ---------------------------------------------------------------------------
__global__ __launch_bounds__(256) void blend_convert_kernel(
    const float* __restrict__ W, const float* __restrict__ cb,
    const float* __restrict__ x,
    unsigned short* __restrict__ wb, unsigned short* __restrict__ xb)
{
    float c[8];
#pragma unroll
    for (int e = 0; e < 8; ++e) c[e] = cb[e];
    const unsigned per_layer = 4194304u;            // 2048*2048
    const unsigned wtotal4 = 3u * (per_layer >> 2); // 3,145,728 float4 units
    const unsigned xtotal4 = 2097152u;              // 8M / 4
    const unsigned total = wtotal4 + xtotal4;
    unsigned stride = gridDim.x * blockDim.x;
    for (unsigned i = blockIdx.x * blockDim.x + threadIdx.x; i < total; i += stride) {
        if (i < wtotal4) {
            unsigned layer = i >> 20;                // per_layer/4 = 2^20
            unsigned off = (i & 1048575u) << 2;      // element offset in layer
            const float* base = W + (size_t)layer * 8u * per_layer + off;
            float4 s = make_float4(0.f, 0.f, 0.f, 0.f);
#pragma unroll
            for (int e = 0; e < 8; ++e) {
                float4 v = *(const float4*)(base + (size_t)e * per_layer);
                s.x += c[e] * v.x; s.y += c[e] * v.y;
                s.z += c[e] * v.z; s.w += c[e] * v.w;
            }
            ushort4 o;
            o.x = f2bf(s.x); o.y = f2bf(s.y); o.z = f2bf(s.z); o.w = f2bf(s.w);
            *(ushort4*)(wb + (size_t)layer * per_layer + off) = o;
        } else {
            unsigned j = (i - wtotal4) << 2;
            float4 v = *(const float4*)(x + j);
            ushort4 o;
            o.x = f2bf(v.x); o.y = f2bf(v.y); o.z = f2bf(v.z); o.w = f2bf(v.w);
            *(ushort4*)(xb + j) = o;
        }
    }
}

// ---------------------------------------------------------------------------
// Kernel 2: 256x128 2-phase-per-K-tile bf16 GEMM.
//   C[M,N] = A[M,K] * Bw[N,K]^T + bias, optional ELU.
// grid = 16x16 = 256 blocks -> all 256 CUs. 512 threads = 8 waves
// (WARPS_M=2 x WARPS_N=4); wave output 128x32: rows qm*128+wr*64+m*16,
// cols wc*32+n*16. Phase(qm) computes one A-half vs full B (16 MFMA).
// B fragments live in regs across both phases.
// LDS 96KB: per buf {A[256][64] 32KB, B[128][64] 16KB}, XOR-16B swizzled.
// Staging: 6x 8KB gload_lds per K-tile; steady-state vmcnt(2):
//   Pa(t) issues t+1:{B0,A2,A3}; Pb(t) issues t+1:{B1} + t+2:{A0,A1};
//   end-of-Pb vmcnt(2) => tile t+1 fully landed, t+2's A0,A1 in flight.
// WAR ledger: nxt regions last read in iter t-1 (safe at Pa/Pb issue);
//   cur A0,A1 (t+2 target) last read by Pa(t), Pb issues after Pa end-barrier.
// ---------------------------------------------------------------------------
#define BARR() do { asm volatile("" ::: "memory"); __builtin_amdgcn_s_barrier(); asm volatile("" ::: "memory"); } while (0)
#define SP(N) __builtin_amdgcn_s_setprio(N)
#define VMC(N) asm volatile("s_waitcnt vmcnt(" #N ")" ::: "memory")

template<int ACT, typename OutT>
__global__ __launch_bounds__(512, 2) void gemm_bn128(
    const unsigned short* __restrict__ A,   // M x K bf16 bits
    const unsigned short* __restrict__ Bw,  // N x K bf16 bits
    const float* __restrict__ bias,         // N
    OutT* __restrict__ C)                   // M x N
{
    __shared__ __align__(16) unsigned short lds[49152];   // 96 KB
    char* ldsc = (char*)lds;

    const int tid = threadIdx.x;
    const int wid = tid >> 6;
    const int lane = tid & 63;
    const int wr = wid >> 2;      // 0..1 (M)
    const int wc = wid & 3;       // 0..3 (N)

    // bijective XCD-chunked swizzle: XCD k gets wg in [k*32,(k+1)*32)
    // = 2 N-panels x 16 M-tiles -> B panels (1MB) L2-resident per XCD.
    const int wg = (blockIdx.x & 7) * 32 + (blockIdx.x >> 3);
    const size_t blockM = (size_t)(wg & 15) * 256;
    const size_t blockN = (size_t)(wg >> 4) * 128;

    // ds_read addressing: swizzled 16B slot within a 128B row.
    const int sw = (lane & 7) << 4;          // (row&7)<<4; row&7 == lane&7
    const int ck = (lane >> 4) << 4;         // k-slot byte base
    const int rAb = wr * 64 + (lane & 15);   // + qm*128 + m*16
    const int rBb = wc * 32 + (lane & 15);   // + n*16

    // staging: thread t writes LDS linear bytes [tid*16, tid*16+16) of an
    // 8KB 64-row stage; source column pre-XORed so
    // LDS[row][slot] = G[row][slot ^ (row&7)].
    const int srow = tid >> 3;                       // 0..63
    const int scol = ((tid & 7) ^ (srow & 7)) << 3;  // element offset
    const unsigned short* aStage = A + (blockM + srow) * KDIM + scol;
    const unsigned short* bStage = Bw + (blockN + srow) * KDIM + scol;

#define STAGE_AS(BUF, S, KT) do { \
    const unsigned short* g_ = aStage + (size_t)(S) * 64 * KDIM + (size_t)(KT) * 64; \
    __builtin_amdgcn_global_load_lds((const __attribute__((address_space(1))) void*)g_, \
        (__attribute__((address_space(3))) void*)(ldsc + (BUF) * 49152 + (S) * 8192 + tid * 16), \
        16, 0, 0); \
} while (0)

#define STAGE_BS(BUF, S, KT) do { \
    const unsigned short* g_ = bStage + (size_t)(S) * 64 * KDIM + (size_t)(KT) * 64; \
    __builtin_amdgcn_global_load_lds((const __attribute__((address_space(1))) void*)g_, \
        (__attribute__((address_space(3))) void*)(ldsc + (BUF) * 49152 + 32768 + (S) * 8192 + tid * 16), \
        16, 0, 0); \
} while (0)

#define RD_A(BUF, QM, M, KK) \
    (*(const bf16x8*)(ldsc + (BUF) * 49152 + ((QM) * 128 + rAb + (M) * 16) * 128 + (((KK) * 64 + ck) ^ sw)))
#define RD_B(BUF, N, KK) \
    (*(const bf16x8*)(ldsc + (BUF) * 49152 + 32768 + (rBb + (N) * 16) * 128 + (((KK) * 64 + ck) ^ sw)))

    f32x4 acc[2][4][2];
#pragma unroll
    for (int q = 0; q < 2; ++q)
#pragma unroll
        for (int m = 0; m < 4; ++m)
#pragma unroll
            for (int n = 0; n < 2; ++n) acc[q][m][n] = (f32x4){0.f, 0.f, 0.f, 0.f};

    bf16x8 af[4][2], bfr[2][2];

#define READ_AQ(BUF, QM) do { _Pragma("unroll") for (int m_ = 0; m_ < 4; ++m_) { \
    af[m_][0] = RD_A(BUF, QM, m_, 0); af[m_][1] = RD_A(BUF, QM, m_, 1); } } while (0)
#define READ_BF(BUF) do { \
    bfr[0][0] = RD_B(BUF, 0, 0); bfr[0][1] = RD_B(BUF, 0, 1); \
    bfr[1][0] = RD_B(BUF, 1, 0); bfr[1][1] = RD_B(BUF, 1, 1); } while (0)
#define DO_MFMA16(QM) do { _Pragma("unroll") for (int m_ = 0; m_ < 4; ++m_) \
    _Pragma("unroll") for (int n_ = 0; n_ < 2; ++n_) { \
        acc[QM][m_][n_] = __builtin_amdgcn_mfma_f32_16x16x32_bf16(af[m_][0], bfr[n_][0], acc[QM][m_][n_], 0, 0, 0); \
        acc[QM][m_][n_] = __builtin_amdgcn_mfma_f32_16x16x32_bf16(af[m_][1], bfr[n_][1], acc[QM][m_][n_], 0, 0, 0); } } while (0)

    // ---- prologue: tile0 all 6 stages -> buf0; tile1 A0,A1 -> buf1 ----
    STAGE_AS(0, 0, 0); STAGE_AS(0, 1, 0); STAGE_BS(0, 0, 0);
    STAGE_AS(0, 2, 0); STAGE_AS(0, 3, 0); STAGE_BS(0, 1, 0);
    STAGE_AS(1, 0, 1); STAGE_AS(1, 1, 1);
    VMC(2);                       // tile0 landed; tile1's A0,A1 in flight
    BARR();

#pragma unroll 1
    for (int t = 0; t < KTILES; ++t) {
        const int cur = t & 1, nxt = cur ^ 1;
        const int t1 = t + 1, t2 = t + 2;
        // ---- Pa: qm=0 of tile t; stage t+1 {B0,A2,A3} -> nxt ----
        READ_AQ(cur, 0);
        READ_BF(cur);
        if (t1 < KTILES) { STAGE_BS(nxt, 0, t1); STAGE_AS(nxt, 2, t1); STAGE_AS(nxt, 3, t1); }
        BARR(); SP(1); DO_MFMA16(0); SP(0); BARR();
        // ---- Pb: qm=1 (B regs reused); stage t+1 {B1} -> nxt, t+2 {A0,A1} -> cur ----
        READ_AQ(cur, 1);
        if (t1 < KTILES) STAGE_BS(nxt, 1, t1);
        if (t2 < KTILES) { STAGE_AS(cur, 0, t2); STAGE_AS(cur, 1, t2); }
        BARR(); SP(1); DO_MFMA16(1); SP(0);
        if (t2 < KTILES) { VMC(2); }            // tile t+1 fully landed
        else if (t1 < KTILES) { VMC(0); }       // tail: drain last tile
        BARR();
    }

    // ---- epilogue: C/D layout col=lane&15 (N), row=(lane>>4)*4+reg (M) ----
    const int crow = (lane >> 4) * 4;
    const int ccol = lane & 15;
#pragma unroll
    for (int qm = 0; qm < 2; ++qm)
#pragma unroll
        for (int m = 0; m < 4; ++m)
#pragma unroll
            for (int n = 0; n < 2; ++n) {
                const size_t col = blockN + wc * 32 + n * 16 + ccol;
                const float bv = bias[col];
#pragma unroll
                for (int r = 0; r < 4; ++r) {
                    const size_t row = blockM + qm * 128 + wr * 64 + m * 16 + crow + r;
                    float v = acc[qm][m][n][r] + bv;
                    if (ACT) v = v > 0.f ? v : expm1f(v);
                    if constexpr (sizeof(OutT) == 2) {
                        C[row * NDIM + col] = (OutT)f2bf(v);
                    } else {
                        C[row * NDIM + col] = (OutT)v;
                    }
                }
            }
#undef STAGE_AS
#undef STAGE_BS
#undef RD_A
#undef RD_B
#undef READ_AQ
#undef READ_BF
#undef DO_MFMA16
}

// ---------------------------------------------------------------------------
// Launch: blend+convert, then 3 chained GEMMs.
// Workspace (ushort units): wb[3*4194304] weights, xb[8388608], y0[8388608].
// ---------------------------------------------------------------------------
extern "C" void kernel_launch(void* const* d_in, const int* in_sizes, int n_in,
                              void* d_out, int out_size, void* d_ws, size_t ws_size,
                              hipStream_t stream) {
    const float* blendw = (const float*)d_in[0];   // (8,)
    const float* x      = (const float*)d_in[1];   // (4096, 2048)
    const float* W      = (const float*)d_in[2];   // (3, 8, 2048, 2048)
    const float* Bb     = (const float*)d_in[3];   // (3, 2048)
    float* out = (float*)d_out;                    // (4096, 2048) f32

    unsigned short* wb = (unsigned short*)d_ws;
    unsigned short* xb = wb + (size_t)3 * 4194304;
    unsigned short* y0 = xb + 8388608;
    unsigned short* y1 = xb;   // reuse: xb dead after GEMM0

    blend_convert_kernel<<<2048, 256, 0, stream>>>(W, blendw, x, wb, xb);

    const int grid = (MDIM / 256) * (NDIM / 128);    // 256 blocks
    gemm_bn128<1, unsigned short><<<grid, 512, 0, stream>>>(xb, wb,               Bb,        y0);
    gemm_bn128<1, unsigned short><<<grid, 512, 0, stream>>>(y0, wb + 4194304,     Bb + 2048, y1);
    gemm_bn128<0, float        ><<<grid, 512, 0, stream>>>(y1, wb + 2 * 4194304,  Bb + 4096, out);
}

// Round 4
// 238.548 us; speedup vs baseline: 1.2836x; 1.0956x over previous
//
#include <hip/hip_runtime.h>
#include <hip/hip_bf16.h>

// Problem dims (fixed by reference): E=8, D=2048, B=4096, 3 layers.
#define MDIM 4096
#define NDIM 2048
#define KDIM 2048
#define KTILES 32          // K / 64

typedef __attribute__((ext_vector_type(8))) short bf16x8;   // 8 bf16 (4 VGPRs)
typedef __attribute__((ext_vector_type(4))) float f32x4;    // MFMA accumulator

__device__ __forceinline__ unsigned short f2bf(float f) {
    unsigned u = __builtin_bit_cast(unsigned, f);
    u += 0x7FFFu + ((u >> 16) & 1u);        // round-to-nearest-even
    return (unsigned short)(u >> 16);
}

// ---------------------------------------------------------------------------
// Kernel 1: blend experts (f32 accumulate, bf16 store) + convert x to bf16.
// Reads 402MB of W + 32MB x -> memory-bound, ~70us.
// ---------------------------------------------------------------------------
__global__ __launch_bounds__(256) void blend_convert_kernel(
    const float* __restrict__ W, const float* __restrict__ cb,
    const float* __restrict__ x,
    unsigned short* __restrict__ wb, unsigned short* __restrict__ xb)
{
    float c[8];
#pragma unroll
    for (int e = 0; e < 8; ++e) c[e] = cb[e];
    const unsigned per_layer = 4194304u;            // 2048*2048
    const unsigned wtotal4 = 3u * (per_layer >> 2); // 3,145,728 float4 units
    const unsigned xtotal4 = 2097152u;              // 8M / 4
    const unsigned total = wtotal4 + xtotal4;
    unsigned stride = gridDim.x * blockDim.x;
    for (unsigned i = blockIdx.x * blockDim.x + threadIdx.x; i < total; i += stride) {
        if (i < wtotal4) {
            unsigned layer = i >> 20;                // per_layer/4 = 2^20
            unsigned off = (i & 1048575u) << 2;      // element offset in layer
            const float* base = W + (size_t)layer * 8u * per_layer + off;
            float4 s = make_float4(0.f, 0.f, 0.f, 0.f);
#pragma unroll
            for (int e = 0; e < 8; ++e) {
                float4 v = *(const float4*)(base + (size_t)e * per_layer);
                s.x += c[e] * v.x; s.y += c[e] * v.y;
                s.z += c[e] * v.z; s.w += c[e] * v.w;
            }
            ushort4 o;
            o.x = f2bf(s.x); o.y = f2bf(s.y); o.z = f2bf(s.z); o.w = f2bf(s.w);
            *(ushort4*)(wb + (size_t)layer * per_layer + off) = o;
        } else {
            unsigned j = (i - wtotal4) << 2;
            float4 v = *(const float4*)(x + j);
            ushort4 o;
            o.x = f2bf(v.x); o.y = f2bf(v.y); o.z = f2bf(v.z); o.w = f2bf(v.w);
            *(ushort4*)(xb + j) = o;
        }
    }
}

// ---------------------------------------------------------------------------
// Kernel 2: 256x128 bf16 GEMM, triple-buffered LDS, 2-tile-deep prefetch.
//   C[M,N] = A[M,K] * Bw[N,K]^T + bias, optional ELU.
// grid = 16x16 = 256 blocks -> all 256 CUs. 512 threads = 8 waves
// (2 M-rows x 4 N-cols); wave output 128x32.
// LDS 144KB: 3 bufs x {A[256][64] 32KB, B[128][64] 16KB}, XOR-16B swizzled.
// Pipeline: during tile t, issue all 6 stages of tile t+2 into buf (t+2)%3;
// end-of-iter vmcnt(6) => tile t+1 fully landed, t+2's 6 loads in flight
// (~4 phases of latency cover for LLC-hit A-panel streams).
// Hazards: stage target buf (t+2)%3 was read in iter t-1 (barrier-separated);
// RAW: per-wave vmcnt(6) + end-of-iter barrier => all waves see t+1 landed.
// ---------------------------------------------------------------------------
#define BARR() do { asm volatile("" ::: "memory"); __builtin_amdgcn_s_barrier(); asm volatile("" ::: "memory"); } while (0)
#define SP(N) __builtin_amdgcn_s_setprio(N)
#define VMC(N) asm volatile("s_waitcnt vmcnt(" #N ")" ::: "memory")

template<int ACT, typename OutT>
__global__ __launch_bounds__(512, 2) void gemm_bn128(
    const unsigned short* __restrict__ A,   // M x K bf16 bits
    const unsigned short* __restrict__ Bw,  // N x K bf16 bits
    const float* __restrict__ bias,         // N
    OutT* __restrict__ C)                   // M x N
{
    __shared__ __align__(16) unsigned short lds[73728];   // 144 KB
    char* ldsc = (char*)lds;

    const int tid = threadIdx.x;
    const int wid = tid >> 6;
    const int lane = tid & 63;
    const int wr = wid >> 2;      // 0..1 (M)
    const int wc = wid & 3;       // 0..3 (N)

    // bijective XCD-chunked swizzle: XCD k gets wg in [k*32,(k+1)*32)
    // = 2 N-panels x 16 M-tiles -> B panels (1MB) L2-resident per XCD.
    const int wg = (blockIdx.x & 7) * 32 + (blockIdx.x >> 3);
    const size_t blockM = (size_t)(wg & 15) * 256;
    const size_t blockN = (size_t)(wg >> 4) * 128;

    // ds_read addressing: swizzled 16B slot within a 128B row.
    const int sw = (lane & 7) << 4;          // (row&7)<<4; row&7 == lane&7
    const int ck = (lane >> 4) << 4;         // k-slot byte base
    const int rAb = wr * 64 + (lane & 15);   // + qm*128 + m*16
    const int rBb = wc * 32 + (lane & 15);   // + n*16

    // staging: thread t writes LDS linear bytes [tid*16, tid*16+16) of an
    // 8KB 64-row stage; source column pre-XORed so
    // LDS[row][slot] = G[row][slot ^ (row&7)].
    const int srow = tid >> 3;                       // 0..63
    const int scol = ((tid & 7) ^ (srow & 7)) << 3;  // element offset
    const unsigned short* aStage = A + (blockM + srow) * KDIM + scol;
    const unsigned short* bStage = Bw + (blockN + srow) * KDIM + scol;

#define STAGE_AS(BUF, S, KT) do { \
    const unsigned short* g_ = aStage + (size_t)(S) * 64 * KDIM + (size_t)(KT) * 64; \
    __builtin_amdgcn_global_load_lds((const __attribute__((address_space(1))) void*)g_, \
        (__attribute__((address_space(3))) void*)(ldsc + (BUF) * 49152 + (S) * 8192 + tid * 16), \
        16, 0, 0); \
} while (0)

#define STAGE_BS(BUF, S, KT) do { \
    const unsigned short* g_ = bStage + (size_t)(S) * 64 * KDIM + (size_t)(KT) * 64; \
    __builtin_amdgcn_global_load_lds((const __attribute__((address_space(1))) void*)g_, \
        (__attribute__((address_space(3))) void*)(ldsc + (BUF) * 49152 + 32768 + (S) * 8192 + tid * 16), \
        16, 0, 0); \
} while (0)

#define RD_A(BUF, QM, M, KK) \
    (*(const bf16x8*)(ldsc + (BUF) * 49152 + ((QM) * 128 + rAb + (M) * 16) * 128 + (((KK) * 64 + ck) ^ sw)))
#define RD_B(BUF, N, KK) \
    (*(const bf16x8*)(ldsc + (BUF) * 49152 + 32768 + (rBb + (N) * 16) * 128 + (((KK) * 64 + ck) ^ sw)))

    f32x4 acc[2][4][2];
#pragma unroll
    for (int q = 0; q < 2; ++q)
#pragma unroll
        for (int m = 0; m < 4; ++m)
#pragma unroll
            for (int n = 0; n < 2; ++n) acc[q][m][n] = (f32x4){0.f, 0.f, 0.f, 0.f};

    bf16x8 af[4][2], bfr[2][2];

#define READ_AQ(BUF, QM) do { _Pragma("unroll") for (int m_ = 0; m_ < 4; ++m_) { \
    af[m_][0] = RD_A(BUF, QM, m_, 0); af[m_][1] = RD_A(BUF, QM, m_, 1); } } while (0)
#define READ_BF(BUF) do { \
    bfr[0][0] = RD_B(BUF, 0, 0); bfr[0][1] = RD_B(BUF, 0, 1); \
    bfr[1][0] = RD_B(BUF, 1, 0); bfr[1][1] = RD_B(BUF, 1, 1); } while (0)
#define DO_MFMA16(QM) do { _Pragma("unroll") for (int m_ = 0; m_ < 4; ++m_) \
    _Pragma("unroll") for (int n_ = 0; n_ < 2; ++n_) { \
        acc[QM][m_][n_] = __builtin_amdgcn_mfma_f32_16x16x32_bf16(af[m_][0], bfr[n_][0], acc[QM][m_][n_], 0, 0, 0); \
        acc[QM][m_][n_] = __builtin_amdgcn_mfma_f32_16x16x32_bf16(af[m_][1], bfr[n_][1], acc[QM][m_][n_], 0, 0, 0); } } while (0)

    // ---- prologue: tile0 -> buf0 (6 stages), tile1 -> buf1 (6 stages) ----
    STAGE_AS(0, 0, 0); STAGE_AS(0, 1, 0); STAGE_AS(0, 2, 0); STAGE_AS(0, 3, 0);
    STAGE_BS(0, 0, 0); STAGE_BS(0, 1, 0);
    STAGE_AS(1, 0, 1); STAGE_AS(1, 1, 1); STAGE_AS(1, 2, 1); STAGE_AS(1, 3, 1);
    STAGE_BS(1, 0, 1); STAGE_BS(1, 1, 1);
    VMC(6);                       // tile0 landed; tile1's 6 in flight
    BARR();

    int cur = 0;
#pragma unroll 1
    for (int t = 0; t < KTILES; ++t) {
        int stb = cur + 2; if (stb >= 3) stb -= 3;   // (t+2)%3
        const int t1 = t + 1, t2 = t + 2;
        // ---- Pa: qm=0 of tile t; issue 3 stages of t+2 ----
        READ_AQ(cur, 0);
        READ_BF(cur);
        if (t2 < KTILES) { STAGE_AS(stb, 0, t2); STAGE_AS(stb, 1, t2); STAGE_BS(stb, 0, t2); }
        BARR(); SP(1); DO_MFMA16(0); SP(0); BARR();
        // ---- Pb: qm=1 (B regs reused); issue remaining 3 stages of t+2 ----
        READ_AQ(cur, 1);
        if (t2 < KTILES) { STAGE_AS(stb, 2, t2); STAGE_AS(stb, 3, t2); STAGE_BS(stb, 1, t2); }
        BARR(); SP(1); DO_MFMA16(1); SP(0);
        if (t2 < KTILES) { VMC(6); }            // tile t+1 fully landed
        else if (t1 < KTILES) { VMC(0); }       // tail: drain last tile
        BARR();
        cur = cur + 1; if (cur >= 3) cur = 0;
    }

    // ---- epilogue: C/D layout col=lane&15 (N), row=(lane>>4)*4+reg (M) ----
    const int crow = (lane >> 4) * 4;
    const int ccol = lane & 15;
#pragma unroll
    for (int qm = 0; qm < 2; ++qm)
#pragma unroll
        for (int m = 0; m < 4; ++m)
#pragma unroll
            for (int n = 0; n < 2; ++n) {
                const size_t col = blockN + wc * 32 + n * 16 + ccol;
                const float bv = bias[col];
#pragma unroll
                for (int r = 0; r < 4; ++r) {
                    const size_t row = blockM + qm * 128 + wr * 64 + m * 16 + crow + r;
                    float v = acc[qm][m][n][r] + bv;
                    if (ACT) v = v > 0.f ? v : expm1f(v);
                    if constexpr (sizeof(OutT) == 2) {
                        C[row * NDIM + col] = (OutT)f2bf(v);
                    } else {
                        C[row * NDIM + col] = (OutT)v;
                    }
                }
            }
#undef STAGE_AS
#undef STAGE_BS
#undef RD_A
#undef RD_B
#undef READ_AQ
#undef READ_BF
#undef DO_MFMA16
}

// ---------------------------------------------------------------------------
// Launch: blend+convert, then 3 chained GEMMs.
// Workspace (ushort units): wb[3*4194304] weights, xb[8388608], y0[8388608].
// ---------------------------------------------------------------------------
extern "C" void kernel_launch(void* const* d_in, const int* in_sizes, int n_in,
                              void* d_out, int out_size, void* d_ws, size_t ws_size,
                              hipStream_t stream) {
    const float* blendw = (const float*)d_in[0];   // (8,)
    const float* x      = (const float*)d_in[1];   // (4096, 2048)
    const float* W      = (const float*)d_in[2];   // (3, 8, 2048, 2048)
    const float* Bb     = (const float*)d_in[3];   // (3, 2048)
    float* out = (float*)d_out;                    // (4096, 2048) f32

    unsigned short* wb = (unsigned short*)d_ws;
    unsigned short* xb = wb + (size_t)3 * 4194304;
    unsigned short* y0 = xb + 8388608;
    unsigned short* y1 = xb;   // reuse: xb dead after GEMM0

    blend_convert_kernel<<<2048, 256, 0, stream>>>(W, blendw, x, wb, xb);

    const int grid = (MDIM / 256) * (NDIM / 128);    // 256 blocks
    gemm_bn128<1, unsigned short><<<grid, 512, 0, stream>>>(xb, wb,               Bb,        y0);
    gemm_bn128<1, unsigned short><<<grid, 512, 0, stream>>>(y0, wb + 4194304,     Bb + 2048, y1);
    gemm_bn128<0, float        ><<<grid, 512, 0, stream>>>(y1, wb + 2 * 4194304,  Bb + 4096, out);
}

// Round 5
// 232.213 us; speedup vs baseline: 1.3186x; 1.0273x over previous
//
#include <hip/hip_runtime.h>
#include <hip/hip_bf16.h>

// Problem dims (fixed by reference): E=8, D=2048, B=4096, 3 layers.
#define MDIM 4096
#define NDIM 2048
#define KDIM 2048
#define KTILES 32          // K / 64

typedef __attribute__((ext_vector_type(8))) short bf16x8;   // 8 bf16 (4 VGPRs)
typedef __attribute__((ext_vector_type(4))) float f32x4;    // MFMA accumulator

__device__ __forceinline__ unsigned short f2bf(float f) {
    unsigned u = __builtin_bit_cast(unsigned, f);
    u += 0x7FFFu + ((u >> 16) & 1u);        // round-to-nearest-even
    return (unsigned short)(u >> 16);
}

// ---------------------------------------------------------------------------
// Kernel 1: blend experts (f32 accumulate, bf16 store) + convert x to bf16.
// Reads 402MB of W + 32MB x -> memory-bound, ~70us (HBM roofline).
// ---------------------------------------------------------------------------
__global__ __launch_bounds__(256) void blend_convert_kernel(
    const float* __restrict__ W, const float* __restrict__ cb,
    const float* __restrict__ x,
    unsigned short* __restrict__ wb, unsigned short* __restrict__ xb)
{
    float c[8];
#pragma unroll
    for (int e = 0; e < 8; ++e) c[e] = cb[e];
    const unsigned per_layer = 4194304u;            // 2048*2048
    const unsigned wtotal4 = 3u * (per_layer >> 2); // 3,145,728 float4 units
    const unsigned xtotal4 = 2097152u;              // 8M / 4
    const unsigned total = wtotal4 + xtotal4;
    unsigned stride = gridDim.x * blockDim.x;
    for (unsigned i = blockIdx.x * blockDim.x + threadIdx.x; i < total; i += stride) {
        if (i < wtotal4) {
            unsigned layer = i >> 20;                // per_layer/4 = 2^20
            unsigned off = (i & 1048575u) << 2;      // element offset in layer
            const float* base = W + (size_t)layer * 8u * per_layer + off;
            float4 s = make_float4(0.f, 0.f, 0.f, 0.f);
#pragma unroll
            for (int e = 0; e < 8; ++e) {
                float4 v = *(const float4*)(base + (size_t)e * per_layer);
                s.x += c[e] * v.x; s.y += c[e] * v.y;
                s.z += c[e] * v.z; s.w += c[e] * v.w;
            }
            ushort4 o;
            o.x = f2bf(s.x); o.y = f2bf(s.y); o.z = f2bf(s.z); o.w = f2bf(s.w);
            *(ushort4*)(wb + (size_t)layer * per_layer + off) = o;
        } else {
            unsigned j = (i - wtotal4) << 2;
            float4 v = *(const float4*)(x + j);
            ushort4 o;
            o.x = f2bf(v.x); o.y = f2bf(v.y); o.z = f2bf(v.z); o.w = f2bf(v.w);
            *(ushort4*)(xb + j) = o;
        }
    }
}

// ---------------------------------------------------------------------------
// Kernel 2: 256x128 bf16 GEMM, triple-buffered LDS, 2-tile-deep prefetch,
// ONE barrier per K-tile (waves free-run within an iteration so LDS reads
// and MFMA overlap across waves).
//   C[M,N] = A[M,K] * Bw[N,K]^T + bias, optional ELU.
// grid = 16x16 = 256 blocks -> all 256 CUs. 512 threads = 8 waves
// (4 M-rows x 2 N-cols); wave tile 64x64 (acc 4x4) -> 16 ds_read_b128 +
// 32 MFMA per wave per K-tile (LDS pipe ~= MFMA pipe, both ~1240 cyc/CU).
// LDS 144KB: 3 bufs x {A[256][64] 32KB, B[128][64] 16KB}, XOR-16B swizzled.
// Hazard ledger (single barrier valid): iter t reads buf t%3, stages buf
// (t+2)%3 which was read in iter t-1; a wave passes the end-of-(t-1) barrier
// only after its reads are consumed (lgkmcnt before its MFMA) -> WAR safe.
// RAW: end-of-iter VMC(6) => tile t+1 landed; barrier publishes to all waves.
// ---------------------------------------------------------------------------
#define BARR() do { asm volatile("" ::: "memory"); __builtin_amdgcn_s_barrier(); asm volatile("" ::: "memory"); } while (0)
#define SP(N) __builtin_amdgcn_s_setprio(N)
#define VMC(N) asm volatile("s_waitcnt vmcnt(" #N ")" ::: "memory")

template<int ACT, typename OutT>
__global__ __launch_bounds__(512, 2) void gemm_bn128(
    const unsigned short* __restrict__ A,   // M x K bf16 bits
    const unsigned short* __restrict__ Bw,  // N x K bf16 bits
    const float* __restrict__ bias,         // N
    OutT* __restrict__ C)                   // M x N
{
    __shared__ __align__(16) unsigned short lds[73728];   // 144 KB
    char* ldsc = (char*)lds;

    const int tid = threadIdx.x;
    const int wid = tid >> 6;
    const int lane = tid & 63;
    const int wr = wid >> 1;      // 0..3 (M)
    const int wc = wid & 1;       // 0..1 (N)

    // bijective XCD-chunked swizzle: XCD k gets wg in [k*32,(k+1)*32)
    // = 2 N-panels x 16 M-tiles -> B panels (1MB) L2-resident per XCD.
    const int wg = (blockIdx.x & 7) * 32 + (blockIdx.x >> 3);
    const size_t blockM = (size_t)(wg & 15) * 256;
    const size_t blockN = (size_t)(wg >> 4) * 128;

    // ds_read addressing: swizzled 16B slot within a 128B row.
    const int sw = (lane & 7) << 4;          // (row&7)<<4; row&7 == lane&7
    const int ck = (lane >> 4) << 4;         // k-slot byte base
    const int rAb = wr * 64 + (lane & 15);   // + m*16
    const int rBb = wc * 64 + (lane & 15);   // + n*16

    // staging: thread t writes LDS linear bytes [tid*16, tid*16+16) of an
    // 8KB 64-row stage; source column pre-XORed so
    // LDS[row][slot] = G[row][slot ^ (row&7)].
    const int srow = tid >> 3;                       // 0..63
    const int scol = ((tid & 7) ^ (srow & 7)) << 3;  // element offset
    const unsigned short* aStage = A + (blockM + srow) * KDIM + scol;
    const unsigned short* bStage = Bw + (blockN + srow) * KDIM + scol;

#define STAGE_AS(BUF, S, KT) do { \
    const unsigned short* g_ = aStage + (size_t)(S) * 64 * KDIM + (size_t)(KT) * 64; \
    __builtin_amdgcn_global_load_lds((const __attribute__((address_space(1))) void*)g_, \
        (__attribute__((address_space(3))) void*)(ldsc + (BUF) * 49152 + (S) * 8192 + tid * 16), \
        16, 0, 0); \
} while (0)

#define STAGE_BS(BUF, S, KT) do { \
    const unsigned short* g_ = bStage + (size_t)(S) * 64 * KDIM + (size_t)(KT) * 64; \
    __builtin_amdgcn_global_load_lds((const __attribute__((address_space(1))) void*)g_, \
        (__attribute__((address_space(3))) void*)(ldsc + (BUF) * 49152 + 32768 + (S) * 8192 + tid * 16), \
        16, 0, 0); \
} while (0)

#define RD_A(BUF, M, KK) \
    (*(const bf16x8*)(ldsc + (BUF) * 49152 + ((rAb + (M) * 16)) * 128 + (((KK) * 64 + ck) ^ sw)))
#define RD_B(BUF, N, KK) \
    (*(const bf16x8*)(ldsc + (BUF) * 49152 + 32768 + (rBb + (N) * 16) * 128 + (((KK) * 64 + ck) ^ sw)))

    f32x4 acc[4][4];
#pragma unroll
    for (int m = 0; m < 4; ++m)
#pragma unroll
        for (int n = 0; n < 4; ++n) acc[m][n] = (f32x4){0.f, 0.f, 0.f, 0.f};

    // ---- prologue: tile0 -> buf0 (6 stages), tile1 -> buf1 (6 stages) ----
    STAGE_AS(0, 0, 0); STAGE_AS(0, 1, 0); STAGE_AS(0, 2, 0); STAGE_AS(0, 3, 0);
    STAGE_BS(0, 0, 0); STAGE_BS(0, 1, 0);
    STAGE_AS(1, 0, 1); STAGE_AS(1, 1, 1); STAGE_AS(1, 2, 1); STAGE_AS(1, 3, 1);
    STAGE_BS(1, 0, 1); STAGE_BS(1, 1, 1);
    VMC(6);                       // tile0 landed; tile1's 6 in flight
    BARR();

    int cur = 0;
#pragma unroll 1
    for (int t = 0; t < KTILES; ++t) {
        int stb = cur + 2; if (stb >= 3) stb -= 3;   // (t+2)%3
        const int t1 = t + 1, t2 = t + 2;
        bf16x8 af[4][2], bf[4][2];
#pragma unroll
        for (int m = 0; m < 4; ++m) { af[m][0] = RD_A(cur, m, 0); af[m][1] = RD_A(cur, m, 1); }
#pragma unroll
        for (int n = 0; n < 4; ++n) { bf[n][0] = RD_B(cur, n, 0); bf[n][1] = RD_B(cur, n, 1); }
        if (t2 < KTILES) {
            STAGE_AS(stb, 0, t2); STAGE_AS(stb, 1, t2); STAGE_AS(stb, 2, t2); STAGE_AS(stb, 3, t2);
            STAGE_BS(stb, 0, t2); STAGE_BS(stb, 1, t2);
        }
        SP(1);
#pragma unroll
        for (int kk = 0; kk < 2; ++kk)
#pragma unroll
            for (int m = 0; m < 4; ++m)
#pragma unroll
                for (int n = 0; n < 4; ++n)
                    acc[m][n] = __builtin_amdgcn_mfma_f32_16x16x32_bf16(
                        af[m][kk], bf[n][kk], acc[m][n], 0, 0, 0);
        SP(0);
        if (t2 < KTILES) { VMC(6); }            // tile t+1 fully landed
        else if (t1 < KTILES) { VMC(0); }       // tail: drain last tile
        BARR();
        cur = cur + 1; if (cur >= 3) cur = 0;
    }

    // ---- epilogue: C/D layout col=lane&15 (N), row=(lane>>4)*4+reg (M) ----
    const int crow = (lane >> 4) * 4;
    const int ccol = lane & 15;
#pragma unroll
    for (int m = 0; m < 4; ++m)
#pragma unroll
        for (int n = 0; n < 4; ++n) {
            const size_t col = blockN + wc * 64 + n * 16 + ccol;
            const float bv = bias[col];
#pragma unroll
            for (int r = 0; r < 4; ++r) {
                const size_t row = blockM + wr * 64 + m * 16 + crow + r;
                float v = acc[m][n][r] + bv;
                if (ACT) v = v > 0.f ? v : expm1f(v);
                if constexpr (sizeof(OutT) == 2) {
                    C[row * NDIM + col] = (OutT)f2bf(v);
                } else {
                    C[row * NDIM + col] = (OutT)v;
                }
            }
        }
#undef STAGE_AS
#undef STAGE_BS
#undef RD_A
#undef RD_B
}

// ---------------------------------------------------------------------------
// Launch: blend+convert, then 3 chained GEMMs.
// Workspace (ushort units): wb[3*4194304] weights, xb[8388608], y0[8388608].
// ---------------------------------------------------------------------------
extern "C" void kernel_launch(void* const* d_in, const int* in_sizes, int n_in,
                              void* d_out, int out_size, void* d_ws, size_t ws_size,
                              hipStream_t stream) {
    const float* blendw = (const float*)d_in[0];   // (8,)
    const float* x      = (const float*)d_in[1];   // (4096, 2048)
    const float* W      = (const float*)d_in[2];   // (3, 8, 2048, 2048)
    const float* Bb     = (const float*)d_in[3];   // (3, 2048)
    float* out = (float*)d_out;                    // (4096, 2048) f32

    unsigned short* wb = (unsigned short*)d_ws;
    unsigned short* xb = wb + (size_t)3 * 4194304;
    unsigned short* y0 = xb + 8388608;
    unsigned short* y1 = xb;   // reuse: xb dead after GEMM0

    blend_convert_kernel<<<2048, 256, 0, stream>>>(W, blendw, x, wb, xb);

    const int grid = (MDIM / 256) * (NDIM / 128);    // 256 blocks
    gemm_bn128<1, unsigned short><<<grid, 512, 0, stream>>>(xb, wb,               Bb,        y0);
    gemm_bn128<1, unsigned short><<<grid, 512, 0, stream>>>(y0, wb + 4194304,     Bb + 2048, y1);
    gemm_bn128<0, float        ><<<grid, 512, 0, stream>>>(y1, wb + 2 * 4194304,  Bb + 4096, out);
}